// Round 7
// baseline (124.044 us; speedup 1.0000x reference)
//
#include <hip/hip_runtime.h>
#include <math.h>

// knnLoss: B=4, N=8192, k=3. Brute-force 3-NN, single fused kernel.
// R7: attack the per-CU LDS-return-bandwidth wall (R3-R6 ledger: time ~
// waves/CU x reads/wave x ~11cy; S sources/lane amortizes reads 1/S).
//   - 256 blocks x 512 threads. Block = (source-group of 256) x (8-tile half).
//     g = bid>>1, h = bid&1. Wave w owns tile h*8+w in its own LDS slot;
//     zero barriers in the main body (wave-local lgkmcnt ordering).
//   - S=4 sources per lane; 6 ds_read_b128 per octet (w recomputed in-loop,
//     12 pk-ops amortized over 4 sources). Octet stride 7 float4 (112B) =>
//     8 bank-quad classes: staging writes perfectly balanced, fixup ~free.
//   - Zero-targets replaced by 1e12 sentinel coords (p ~ 3e24 never wins).
//   - Octet-min selection (packed 6-bit idx) + exact per-tile fixup.
//   - Tail: in-block 8-wave merge via LDS; cross-block pair merge via ws
//     (atomicExch partials + pair ticket, winner merges); done-ticket finale.
#define BATCH 4
#define NPTS 8192
#define TILE 512
#define WAVES 8
#define SPB 256               // sources per block = 64 lanes x 4
#define NBLOCKS 256
#define NOCT 64               // octets per tile
#define OCT4 7                // float4 per octet (6 data + 1 pad) = 112 B
#define SLOT4 (NOCT * OCT4)   // 448 float4 per wave slot
#define NPAIRS 128

typedef __attribute__((ext_vector_type(2))) float f2;

__device__ __forceinline__ float min3f(float a, float b, float c) {
    float d;
    asm("v_min3_f32 %0, %1, %2, %3" : "=v"(d) : "v"(a), "v"(b), "v"(c));
    return d;
}

// Branchless insert into sorted ascending triple; 4 ops via med3.
__device__ __forceinline__ void insert3(float d, float& a0, float& a1, float& a2) {
    float h = fmaxf(a1, d);
    float m = __builtin_amdgcn_fmed3f(a0, a1, d);
    a2 = fminf(a2, h);
    a1 = m;
    a0 = fminf(a0, d);
}

// Merge two sorted-ascending triples -> the sorted 3 smallest of the union.
__device__ __forceinline__ void merge33(float a0, float a1, float a2,
                                        float& b0, float& b1, float& b2) {
    float s0 = fminf(a0, b0);
    float h  = fmaxf(a0, b0);
    float m  = fminf(a1, b1);
    float mm = fminf(a2, b2);
    b1 = fminf(h, m);
    b2 = __builtin_amdgcn_fmed3f(h, m, mm);
    b0 = s0;
}

// Exact recompute of one octet (6 float4s, w rebuilt) -> insert into chain.
__device__ __forceinline__ void octet_fix(const float4* ob, f2 nx, f2 ny, f2 nz,
                                          float& c0, float& c1, float& c2) {
    float4 X0 = ob[0], X1 = ob[1], Y0 = ob[2], Y1 = ob[3], Z0 = ob[4], Z1 = ob[5];
    f2 xs0 = (f2){X0.x, X0.y}, xs1 = (f2){X0.z, X0.w};
    f2 xs2 = (f2){X1.x, X1.y}, xs3 = (f2){X1.z, X1.w};
    f2 ys0 = (f2){Y0.x, Y0.y}, ys1 = (f2){Y0.z, Y0.w};
    f2 ys2 = (f2){Y1.x, Y1.y}, ys3 = (f2){Y1.z, Y1.w};
    f2 zs0 = (f2){Z0.x, Z0.y}, zs1 = (f2){Z0.z, Z0.w};
    f2 zs2 = (f2){Z1.x, Z1.y}, zs3 = (f2){Z1.z, Z1.w};
    f2 w0 = zs0 * zs0; w0 = __builtin_elementwise_fma(ys0, ys0, w0);
    w0 = __builtin_elementwise_fma(xs0, xs0, w0);
    f2 w1 = zs1 * zs1; w1 = __builtin_elementwise_fma(ys1, ys1, w1);
    w1 = __builtin_elementwise_fma(xs1, xs1, w1);
    f2 w2 = zs2 * zs2; w2 = __builtin_elementwise_fma(ys2, ys2, w2);
    w2 = __builtin_elementwise_fma(xs2, xs2, w2);
    f2 w3 = zs3 * zs3; w3 = __builtin_elementwise_fma(ys3, ys3, w3);
    w3 = __builtin_elementwise_fma(xs3, xs3, w3);
    f2 pa = __builtin_elementwise_fma(zs0, nz, w0);
    pa = __builtin_elementwise_fma(ys0, ny, pa);
    pa = __builtin_elementwise_fma(xs0, nx, pa);
    f2 pb = __builtin_elementwise_fma(zs1, nz, w1);
    pb = __builtin_elementwise_fma(ys1, ny, pb);
    pb = __builtin_elementwise_fma(xs1, nx, pb);
    f2 pc = __builtin_elementwise_fma(zs2, nz, w2);
    pc = __builtin_elementwise_fma(ys2, ny, pc);
    pc = __builtin_elementwise_fma(xs2, nx, pc);
    f2 pd = __builtin_elementwise_fma(zs3, nz, w3);
    pd = __builtin_elementwise_fma(ys3, ny, pd);
    pd = __builtin_elementwise_fma(xs3, nx, pd);
    insert3(pa.x, c0, c1, c2);
    insert3(pa.y, c0, c1, c2);
    insert3(pb.x, c0, c1, c2);
    insert3(pb.y, c0, c1, c2);
    insert3(pc.x, c0, c1, c2);
    insert3(pc.y, c0, c1, c2);
    insert3(pd.x, c0, c1, c2);
    insert3(pd.y, c0, c1, c2);
}

__global__ __launch_bounds__(512) void knn_fused(const float* __restrict__ src,
                                                 const float* __restrict__ tgt,
                                                 float* __restrict__ acc,
                                                 float* __restrict__ cnt,
                                                 unsigned* __restrict__ done,
                                                 unsigned* __restrict__ pairT,
                                                 float* __restrict__ part,
                                                 float* __restrict__ out) {
    __shared__ float tsf[WAVES * SLOT4 * 4];  // 14336 floats = 57344 B
    const int tid = threadIdx.x;
    const int lane = tid & 63, wave = tid >> 6;
    const int bid = blockIdx.x;
    const int g = bid >> 1;       // source-group 0..127
    const int h = bid & 1;        // tile half 0/1
    const int b = bid >> 6;       // batch (g>>5), uniform per block

    // ---- Stage: lane l owns octet l of this wave's tile (in-register transpose).
    {
        const int tI = h * 8 + wave;
        const float4* tf4 = (const float4*)(tgt +
            ((size_t)b * NPTS + tI * TILE + lane * 8) * 3);
        float4 f0 = tf4[0], f1 = tf4[1], f2v = tf4[2];
        float4 f3 = tf4[3], f4v = tf4[4], f5 = tf4[5];
        float tx[8], ty[8], tz[8];
        tx[0] = f0.x;  ty[0] = f0.y;  tz[0] = f0.z;
        tx[1] = f0.w;  ty[1] = f1.x;  tz[1] = f1.y;
        tx[2] = f1.z;  ty[2] = f1.w;  tz[2] = f2v.x;
        tx[3] = f2v.y; ty[3] = f2v.z; tz[3] = f2v.w;
        tx[4] = f3.x;  ty[4] = f3.y;  tz[4] = f3.z;
        tx[5] = f3.w;  ty[5] = f4v.x; tz[5] = f4v.y;
        tx[6] = f4v.z; ty[6] = f4v.w; tz[6] = f5.x;
        tx[7] = f5.y;  ty[7] = f5.z;  tz[7] = f5.w;
        #pragma unroll
        for (int j = 0; j < 8; ++j) {
            if (!(tx[j] != 0.f || ty[j] != 0.f || tz[j] != 0.f)) {
                tx[j] = 1e12f; ty[j] = 1e12f; tz[j] = 1e12f;  // sentinel
            }
        }
        float4* slot = ((float4*)tsf) + wave * SLOT4 + lane * OCT4;
        slot[0] = make_float4(tx[0], tx[1], tx[2], tx[3]);
        slot[1] = make_float4(tx[4], tx[5], tx[6], tx[7]);
        slot[2] = make_float4(ty[0], ty[1], ty[2], ty[3]);
        slot[3] = make_float4(ty[4], ty[5], ty[6], ty[7]);
        slot[4] = make_float4(tz[0], tz[1], tz[2], tz[3]);
        slot[5] = make_float4(tz[4], tz[5], tz[6], tz[7]);
    }
    // No barrier: each wave reads only the slot it wrote (lgkmcnt orders).

    // ---- Source precompute: lane owns 4 sources g*256 + s*64 + lane.
    f2 nx[4], ny[4], nz[4];
    #pragma unroll
    for (int s = 0; s < 4; ++s) {
        const float* sp = src + ((size_t)g * SPB + s * 64 + lane) * 3;
        float ax = sp[0], ay = sp[1], az = sp[2];
        nx[s] = (f2){-2.f * ax, -2.f * ax};
        ny[s] = (f2){-2.f * ay, -2.f * ay};
        nz[s] = (f2){-2.f * az, -2.f * az};
    }

    // ---- Hot loop: 64 octets, broadcast reads, 4 sources per lane.
    float q0[4], q1[4], q2c[4];
    #pragma unroll
    for (int s = 0; s < 4; ++s) { q0[s] = q1[s] = q2c[s] = 3e38f; }

    const float4* tsv = ((const float4*)tsf) + wave * SLOT4;
    #pragma unroll 2
    for (int o = 0; o < NOCT; ++o) {
        float4 X0 = tsv[7 * o + 0], X1 = tsv[7 * o + 1];
        float4 Y0 = tsv[7 * o + 2], Y1 = tsv[7 * o + 3];
        float4 Z0 = tsv[7 * o + 4], Z1 = tsv[7 * o + 5];
        f2 xs0 = (f2){X0.x, X0.y}, xs1 = (f2){X0.z, X0.w};
        f2 xs2 = (f2){X1.x, X1.y}, xs3 = (f2){X1.z, X1.w};
        f2 ys0 = (f2){Y0.x, Y0.y}, ys1 = (f2){Y0.z, Y0.w};
        f2 ys2 = (f2){Y1.x, Y1.y}, ys3 = (f2){Y1.z, Y1.w};
        f2 zs0 = (f2){Z0.x, Z0.y}, zs1 = (f2){Z0.z, Z0.w};
        f2 zs2 = (f2){Z1.x, Z1.y}, zs3 = (f2){Z1.z, Z1.w};
        // w = |t|^2, once per octet, amortized over 4 sources (12 pk-ops).
        f2 w0 = zs0 * zs0; w0 = __builtin_elementwise_fma(ys0, ys0, w0);
        w0 = __builtin_elementwise_fma(xs0, xs0, w0);
        f2 w1 = zs1 * zs1; w1 = __builtin_elementwise_fma(ys1, ys1, w1);
        w1 = __builtin_elementwise_fma(xs1, xs1, w1);
        f2 w2 = zs2 * zs2; w2 = __builtin_elementwise_fma(ys2, ys2, w2);
        w2 = __builtin_elementwise_fma(xs2, xs2, w2);
        f2 w3 = zs3 * zs3; w3 = __builtin_elementwise_fma(ys3, ys3, w3);
        w3 = __builtin_elementwise_fma(xs3, xs3, w3);
        #pragma unroll
        for (int s = 0; s < 4; ++s) {
            f2 pa = __builtin_elementwise_fma(zs0, nz[s], w0);
            pa = __builtin_elementwise_fma(ys0, ny[s], pa);
            pa = __builtin_elementwise_fma(xs0, nx[s], pa);
            f2 pb = __builtin_elementwise_fma(zs1, nz[s], w1);
            pb = __builtin_elementwise_fma(ys1, ny[s], pb);
            pb = __builtin_elementwise_fma(xs1, nx[s], pb);
            f2 pc = __builtin_elementwise_fma(zs2, nz[s], w2);
            pc = __builtin_elementwise_fma(ys2, ny[s], pc);
            pc = __builtin_elementwise_fma(xs2, nx[s], pc);
            f2 pd = __builtin_elementwise_fma(zs3, nz[s], w3);
            pd = __builtin_elementwise_fma(ys3, ny[s], pd);
            pd = __builtin_elementwise_fma(xs3, nx[s], pd);
            float m1 = min3f(pa.x, pa.y, pb.x);
            float m2 = min3f(pb.y, pc.x, pc.y);
            float m3 = min3f(pd.x, pd.y, m1);
            float m4 = fminf(m2, m3);
            unsigned u = (__float_as_uint(m4) & 0xFFFFFFC0u) | (unsigned)o;
            insert3(__uint_as_float(u), q0[s], q1[s], q2c[s]);
        }
    }

    // ---- Exact fixup (<=3 octets per source), then per-source triple in regs.
    float e0[4], e1[4], e2[4];
    #pragma unroll
    for (int s = 0; s < 4; ++s) {
        e0[s] = 3e38f; e1[s] = 3e38f; e2[s] = 3e38f;
        octet_fix(tsv + 7 * (int)(__float_as_uint(q0[s]) & 63u),
                  nx[s], ny[s], nz[s], e0[s], e1[s], e2[s]);
        octet_fix(tsv + 7 * (int)(__float_as_uint(q1[s]) & 63u),
                  nx[s], ny[s], nz[s], e0[s], e1[s], e2[s]);
        octet_fix(tsv + 7 * (int)(__float_as_uint(q2c[s]) & 63u),
                  nx[s], ny[s], nz[s], e0[s], e1[s], e2[s]);
    }

    // ---- In-block merge: 8 waves' triples per source via LDS (reuse tsf).
    __syncthreads();  // all waves done reading their slots
    #pragma unroll
    for (int s = 0; s < 4; ++s) {
        int idx = ((s * 8 + wave) * 64 + lane) * 3;  // max 6143
        tsf[idx] = e0[s]; tsf[idx + 1] = e1[s]; tsf[idx + 2] = e2[s];
    }
    __syncthreads();

    float a0 = 3e38f, a1 = 3e38f, a2 = 3e38f;
    if (tid < 256) {
        int s = tid >> 6, l = tid & 63;
        int base = ((s * 8 + 0) * 64 + l) * 3;
        a0 = tsf[base]; a1 = tsf[base + 1]; a2 = tsf[base + 2];
        #pragma unroll
        for (int w = 1; w < 8; ++w) {
            int bse = ((s * 8 + w) * 64 + l) * 3;
            merge33(tsf[bse], tsf[bse + 1], tsf[bse + 2], a0, a1, a2);
        }
        // Publish partial triple (device-scope stores via atomicExch).
        size_t pidx = ((size_t)bid * SPB + tid) * 3;
        atomicExch(&part[pidx + 0], a0);
        atomicExch(&part[pidx + 1], a1);
        atomicExch(&part[pidx + 2], a2);
    }
    __threadfence();
    __syncthreads();

    // ---- Pair ticket: second-arriving block of (g) merges both halves.
    unsigned* tflag = (unsigned*)(tsf + 8192);
    if (tid == 0) tflag[0] = atomicAdd(&pairT[g], 1u);
    __syncthreads();
    unsigned t = tflag[0];

    if (t == 1u) {
        float sv = 0.f, cv = 0.f;
        if (tid < 256) {
            size_t qidx = ((size_t)(bid ^ 1) * SPB + tid) * 3;
            float p0 = atomicAdd(&part[qidx + 0], 0.f);
            float p1 = atomicAdd(&part[qidx + 1], 0.f);
            float p2 = atomicAdd(&part[qidx + 2], 0.f);
            merge33(p0, p1, p2, a0, a1, a2);
            const float* sp = src + ((size_t)g * SPB + tid) * 3;
            float sx = sp[0], sy = sp[1], sz = sp[2];
            bool valid = (sx != 0.f) || (sy != 0.f) || (sz != 0.f);
            float qq = sx * sx + sy * sy + sz * sz;  // deferred |s|^2
            sv = valid ? (sqrtf(fmaxf(a0 + qq, 0.f)) + sqrtf(fmaxf(a1 + qq, 0.f)) +
                          sqrtf(fmaxf(a2 + qq, 0.f)))
                       : 0.f;
            cv = valid ? 1.f : 0.f;
        }
        for (int off = 32; off >= 1; off >>= 1) {
            sv += __shfl_down(sv, off);
            cv += __shfl_down(cv, off);
        }
        float* red = tsf + 8200;
        if (lane == 0) { red[wave] = sv; red[wave + 8] = cv; }
        __syncthreads();
        if (tid == 0) {
            float ss = 0.f, cc = 0.f;
            #pragma unroll
            for (int w = 0; w < 8; ++w) { ss += red[w]; cc += red[w + 8]; }
            atomicAdd(&acc[b], ss);
            atomicAdd(&cnt[b], cc);
            __threadfence();
            unsigned dt = atomicAdd(done, 1u);
            if (dt == (unsigned)(NPAIRS - 1)) {
                float loss = 0.f;
                #pragma unroll
                for (int bb = 0; bb < BATCH; ++bb) {
                    float as = atomicAdd(&acc[bb], 0.f);
                    float ac = atomicAdd(&cnt[bb], 0.f);
                    loss += as / (ac * 3.0f);
                }
                out[0] = loss * (1.0f / BATCH);
            }
        }
    }
}

extern "C" void kernel_launch(void* const* d_in, const int* in_sizes, int n_in,
                              void* d_out, int out_size, void* d_ws, size_t ws_size,
                              hipStream_t stream) {
    const float* src = (const float*)d_in[0];
    const float* tgt = (const float*)d_in[1];
    float* out = (float*)d_out;

    // ws: [0,16) acc[4]; [16,32) cnt[4]; [32,36) done; [64,576) pairT[128];
    //     [1024, 1024+786432) partial triples (256 blocks x 256 src x 3 f32).
    float* acc = (float*)d_ws;
    float* cnt = acc + 4;
    unsigned* done = (unsigned*)((char*)d_ws + 32);
    unsigned* pairT = (unsigned*)((char*)d_ws + 64);
    float* part = (float*)((char*)d_ws + 1024);

    hipMemsetAsync(d_ws, 0, 1024, stream);  // zero header (graph-capturable)
    knn_fused<<<dim3(NBLOCKS), 512, 0, stream>>>(src, tgt, acc, cnt, done,
                                                 pairT, part, out);
}

// Round 8
// 101.036 us; speedup vs baseline: 1.2277x; 1.2277x over previous
//
#include <hip/hip_runtime.h>
#include <math.h>

// knnLoss: B=4, N=8192, k=3. Brute-force 3-NN, two kernels (R3 structure).
// R8: LDS-pipe cost model from R3-R7 ledger: runtime ~= waves/CU x b128-
// reads/wave x ~16cy (broadcast ds_read_b128 RF-write bound), valid only at
// >=4 waves/SIMD (R4/R7 at 2 waves/SIMD were latency-bound ~70us).
// => minimize reads/wave at 16 waves/CU: S=4 sources/lane, T=256 targets/wave
//    (32 octets x 6 reads = 192 reads/wave vs R3's 512).
//   - 512 blocks x 512 threads (8 waves), block=(Q quarter, G group, b batch),
//     2 blocks/CU. Wave w stages its own 256-target subtile (3.5KB, OCT4=7
//     padded) -> zero barriers in main body; 28KB LDS total.
//   - w=|t|^2 recomputed per octet (12 pk amortized over 4 sources): 6 reads
//     not 8. Zero-targets -> 1e12 sentinel coords (p~3e24 never selected).
//   - Octet-min selection (5-bit packed idx) + exact 3-octet fixup per source
//     per subtile => exact values; in-block 8-wave merge -> part[Q][3][32768].
//   - knn_merge: 128x256 (R3-proven ~3us), 12 loads/source, finale ticket.
#define BATCH 4
#define NPTS 8192
#define NSRC 32768            // BATCH * NPTS
#define WAVES 8
#define NQ 4                  // target quarters per batch
#define NG 32                 // source groups of 256 per batch
#define NOCTW 32              // octets per wave subtile (256 targets)
#define OCT4 7                // float4 per octet (6 data + 1 pad) = 112 B
#define SLOT4 (NOCTW * OCT4)  // 224 float4 = 3584 B per wave slot
#define MERGE_BLOCKS 128

typedef __attribute__((ext_vector_type(2))) float f2;

__device__ __forceinline__ float min3f(float a, float b, float c) {
    float d;
    asm("v_min3_f32 %0, %1, %2, %3" : "=v"(d) : "v"(a), "v"(b), "v"(c));
    return d;
}

// Branchless insert into sorted ascending triple; 4 ops via med3.
__device__ __forceinline__ void insert3(float d, float& a0, float& a1, float& a2) {
    float h = fmaxf(a1, d);
    float m = __builtin_amdgcn_fmed3f(a0, a1, d);
    a2 = fminf(a2, h);
    a1 = m;
    a0 = fminf(a0, d);
}

// Merge two sorted-ascending triples -> the sorted 3 smallest of the union.
__device__ __forceinline__ void merge33(float a0, float a1, float a2,
                                        float& b0, float& b1, float& b2) {
    float s0 = fminf(a0, b0);
    float h  = fmaxf(a0, b0);
    float m  = fminf(a1, b1);
    float mm = fminf(a2, b2);
    b1 = fminf(h, m);
    b2 = __builtin_amdgcn_fmed3f(h, m, mm);
    b0 = s0;
}

// Exact recompute of one octet (6 float4s, w rebuilt) -> insert into chain.
__device__ __forceinline__ void octet_fix(const float4* ob, f2 nx, f2 ny, f2 nz,
                                          float& c0, float& c1, float& c2) {
    float4 X0 = ob[0], X1 = ob[1], Y0 = ob[2], Y1 = ob[3], Z0 = ob[4], Z1 = ob[5];
    f2 xs0 = (f2){X0.x, X0.y}, xs1 = (f2){X0.z, X0.w};
    f2 xs2 = (f2){X1.x, X1.y}, xs3 = (f2){X1.z, X1.w};
    f2 ys0 = (f2){Y0.x, Y0.y}, ys1 = (f2){Y0.z, Y0.w};
    f2 ys2 = (f2){Y1.x, Y1.y}, ys3 = (f2){Y1.z, Y1.w};
    f2 zs0 = (f2){Z0.x, Z0.y}, zs1 = (f2){Z0.z, Z0.w};
    f2 zs2 = (f2){Z1.x, Z1.y}, zs3 = (f2){Z1.z, Z1.w};
    f2 w0 = zs0 * zs0; w0 = __builtin_elementwise_fma(ys0, ys0, w0);
    w0 = __builtin_elementwise_fma(xs0, xs0, w0);
    f2 w1 = zs1 * zs1; w1 = __builtin_elementwise_fma(ys1, ys1, w1);
    w1 = __builtin_elementwise_fma(xs1, xs1, w1);
    f2 w2 = zs2 * zs2; w2 = __builtin_elementwise_fma(ys2, ys2, w2);
    w2 = __builtin_elementwise_fma(xs2, xs2, w2);
    f2 w3 = zs3 * zs3; w3 = __builtin_elementwise_fma(ys3, ys3, w3);
    w3 = __builtin_elementwise_fma(xs3, xs3, w3);
    f2 pa = __builtin_elementwise_fma(zs0, nz, w0);
    pa = __builtin_elementwise_fma(ys0, ny, pa);
    pa = __builtin_elementwise_fma(xs0, nx, pa);
    f2 pb = __builtin_elementwise_fma(zs1, nz, w1);
    pb = __builtin_elementwise_fma(ys1, ny, pb);
    pb = __builtin_elementwise_fma(xs1, nx, pb);
    f2 pc = __builtin_elementwise_fma(zs2, nz, w2);
    pc = __builtin_elementwise_fma(ys2, ny, pc);
    pc = __builtin_elementwise_fma(xs2, nx, pc);
    f2 pd = __builtin_elementwise_fma(zs3, nz, w3);
    pd = __builtin_elementwise_fma(ys3, ny, pd);
    pd = __builtin_elementwise_fma(xs3, nx, pd);
    insert3(pa.x, c0, c1, c2);
    insert3(pa.y, c0, c1, c2);
    insert3(pb.x, c0, c1, c2);
    insert3(pb.y, c0, c1, c2);
    insert3(pc.x, c0, c1, c2);
    insert3(pc.y, c0, c1, c2);
    insert3(pd.x, c0, c1, c2);
    insert3(pd.y, c0, c1, c2);
}

__global__ __launch_bounds__(512, 4) void knn_partial(const float* __restrict__ src,
                                                      const float* __restrict__ tgt,
                                                      float* __restrict__ part) {
    __shared__ float tsf[WAVES * SLOT4 * 4];  // 28672 floats? no: floats = 8*224*4 = 7168 floats = 28672 B
    const int tid = threadIdx.x;
    const int lane = tid & 63, wave = tid >> 6;
    const int Q = blockIdx.x, G = blockIdx.y, b = blockIdx.z;

    // ---- Stage: lane l loads targets 4l..4l+3 of this wave's 256-target
    // subtile (48B = 3 aligned float4), transposes, writes half-octet h=l&1
    // of octet o=l>>1. OCT4=7 stride spreads bank-quads (R7: conflicts low).
    {
        const float4* tf4 = (const float4*)(tgt +
            ((size_t)b * NPTS + Q * 2048 + wave * 256 + 4 * lane) * 3);
        float4 f0 = tf4[0], f1 = tf4[1], f2v = tf4[2];
        float tx[4], ty[4], tz[4];
        tx[0] = f0.x;  ty[0] = f0.y;  tz[0] = f0.z;
        tx[1] = f0.w;  ty[1] = f1.x;  tz[1] = f1.y;
        tx[2] = f1.z;  ty[2] = f1.w;  tz[2] = f2v.x;
        tx[3] = f2v.y; ty[3] = f2v.z; tz[3] = f2v.w;
        #pragma unroll
        for (int j = 0; j < 4; ++j) {
            if (!(tx[j] != 0.f || ty[j] != 0.f || tz[j] != 0.f)) {
                tx[j] = 1e12f; ty[j] = 1e12f; tz[j] = 1e12f;  // sentinel
            }
        }
        int o = lane >> 1, h = lane & 1;
        float4* slot = ((float4*)tsf) + wave * SLOT4 + o * OCT4;
        slot[0 + h] = make_float4(tx[0], tx[1], tx[2], tx[3]);  // X_h
        slot[2 + h] = make_float4(ty[0], ty[1], ty[2], ty[3]);  // Y_h
        slot[4 + h] = make_float4(tz[0], tz[1], tz[2], tz[3]);  // Z_h
    }
    // No barrier: each wave reads only the slot it wrote (lgkmcnt orders).

    // ---- Source precompute: lane owns 4 sources (b,G): G*256 + s*64 + lane.
    f2 nx[4], ny[4], nz[4];
    #pragma unroll
    for (int s = 0; s < 4; ++s) {
        const float* sp = src + ((size_t)b * NPTS + G * 256 + s * 64 + lane) * 3;
        float ax = sp[0], ay = sp[1], az = sp[2];
        nx[s] = (f2){-2.f * ax, -2.f * ax};
        ny[s] = (f2){-2.f * ay, -2.f * ay};
        nz[s] = (f2){-2.f * az, -2.f * az};
    }

    // ---- Hot loop: 32 octets, 6 broadcast b128 reads each, 4 sources/lane.
    float q0[4], q1[4], q2c[4];
    #pragma unroll
    for (int s = 0; s < 4; ++s) { q0[s] = q1[s] = q2c[s] = 3e38f; }

    const float4* tsv = ((const float4*)tsf) + wave * SLOT4;
    #pragma unroll 2
    for (int o = 0; o < NOCTW; ++o) {
        float4 X0 = tsv[7 * o + 0], X1 = tsv[7 * o + 1];
        float4 Y0 = tsv[7 * o + 2], Y1 = tsv[7 * o + 3];
        float4 Z0 = tsv[7 * o + 4], Z1 = tsv[7 * o + 5];
        f2 xs0 = (f2){X0.x, X0.y}, xs1 = (f2){X0.z, X0.w};
        f2 xs2 = (f2){X1.x, X1.y}, xs3 = (f2){X1.z, X1.w};
        f2 ys0 = (f2){Y0.x, Y0.y}, ys1 = (f2){Y0.z, Y0.w};
        f2 ys2 = (f2){Y1.x, Y1.y}, ys3 = (f2){Y1.z, Y1.w};
        f2 zs0 = (f2){Z0.x, Z0.y}, zs1 = (f2){Z0.z, Z0.w};
        f2 zs2 = (f2){Z1.x, Z1.y}, zs3 = (f2){Z1.z, Z1.w};
        // w = |t|^2 once per octet, amortized over 4 sources.
        f2 w0 = zs0 * zs0; w0 = __builtin_elementwise_fma(ys0, ys0, w0);
        w0 = __builtin_elementwise_fma(xs0, xs0, w0);
        f2 w1 = zs1 * zs1; w1 = __builtin_elementwise_fma(ys1, ys1, w1);
        w1 = __builtin_elementwise_fma(xs1, xs1, w1);
        f2 w2 = zs2 * zs2; w2 = __builtin_elementwise_fma(ys2, ys2, w2);
        w2 = __builtin_elementwise_fma(xs2, xs2, w2);
        f2 w3 = zs3 * zs3; w3 = __builtin_elementwise_fma(ys3, ys3, w3);
        w3 = __builtin_elementwise_fma(xs3, xs3, w3);
        #pragma unroll
        for (int s = 0; s < 4; ++s) {
            f2 pa = __builtin_elementwise_fma(zs0, nz[s], w0);
            pa = __builtin_elementwise_fma(ys0, ny[s], pa);
            pa = __builtin_elementwise_fma(xs0, nx[s], pa);
            f2 pb = __builtin_elementwise_fma(zs1, nz[s], w1);
            pb = __builtin_elementwise_fma(ys1, ny[s], pb);
            pb = __builtin_elementwise_fma(xs1, nx[s], pb);
            f2 pc = __builtin_elementwise_fma(zs2, nz[s], w2);
            pc = __builtin_elementwise_fma(ys2, ny[s], pc);
            pc = __builtin_elementwise_fma(xs2, nx[s], pc);
            f2 pd = __builtin_elementwise_fma(zs3, nz[s], w3);
            pd = __builtin_elementwise_fma(ys3, ny[s], pd);
            pd = __builtin_elementwise_fma(xs3, nx[s], pd);
            float m1 = min3f(pa.x, pa.y, pb.x);
            float m2 = min3f(pb.y, pc.x, pc.y);
            float m3 = min3f(pd.x, pd.y, m1);
            float m4 = fminf(m2, m3);
            unsigned u = (__float_as_uint(m4) & 0xFFFFFFE0u) | (unsigned)o;
            insert3(__uint_as_float(u), q0[s], q1[s], q2c[s]);
        }
    }

    // ---- Exact fixup (<=3 distinct octets per source; chain has 3 distinct
    // octet entries since each octet inserts exactly one packed value).
    float e0[4], e1[4], e2[4];
    #pragma unroll
    for (int s = 0; s < 4; ++s) {
        e0[s] = 3e38f; e1[s] = 3e38f; e2[s] = 3e38f;
        octet_fix(tsv + 7 * (int)(__float_as_uint(q0[s]) & 31u),
                  nx[s], ny[s], nz[s], e0[s], e1[s], e2[s]);
        octet_fix(tsv + 7 * (int)(__float_as_uint(q1[s]) & 31u),
                  nx[s], ny[s], nz[s], e0[s], e1[s], e2[s]);
        octet_fix(tsv + 7 * (int)(__float_as_uint(q2c[s]) & 31u),
                  nx[s], ny[s], nz[s], e0[s], e1[s], e2[s]);
    }

    // ---- In-block merge across 8 waves (reuse tsf; needs 6144 floats).
    __syncthreads();
    #pragma unroll
    for (int s = 0; s < 4; ++s) {
        int idx = ((s * 8 + wave) * 64 + lane) * 3;
        tsf[idx] = e0[s]; tsf[idx + 1] = e1[s]; tsf[idx + 2] = e2[s];
    }
    __syncthreads();

    if (tid < 256) {
        int s = tid >> 6, l = tid & 63;
        int base = (s * 8 * 64 + l) * 3;
        float a0 = tsf[base], a1 = tsf[base + 1], a2 = tsf[base + 2];
        #pragma unroll
        for (int w = 1; w < 8; ++w) {
            int bse = ((s * 8 + w) * 64 + l) * 3;
            merge33(tsf[bse], tsf[bse + 1], tsf[bse + 2], a0, a1, a2);
        }
        size_t gsrc = (size_t)b * NPTS + G * 256 + tid;
        part[((size_t)Q * 3 + 0) * NSRC + gsrc] = a0;
        part[((size_t)Q * 3 + 1) * NSRC + gsrc] = a1;
        part[((size_t)Q * 3 + 2) * NSRC + gsrc] = a2;
    }
}

// R3-proven merge geometry (128 x 256), now 12 partials per source.
__global__ __launch_bounds__(256) void knn_merge(const float* __restrict__ src,
                                                 const float* __restrict__ part,
                                                 float* __restrict__ acc,
                                                 float* __restrict__ cnt,
                                                 unsigned* __restrict__ ticket,
                                                 float* __restrict__ out) {
    const int gid = blockIdx.x * 256 + threadIdx.x;  // 0 .. NSRC-1
    const int b = gid >> 13;                         // uniform per block

    float t0[2], t1[2], t2[2];
    #pragma unroll
    for (int c = 0; c < 2; ++c) { t0[c] = t1[c] = t2[c] = 3e38f; }
    #pragma unroll
    for (int q = 0; q < NQ * 3; ++q)
        insert3(part[(size_t)q * NSRC + gid], t0[q & 1], t1[q & 1], t2[q & 1]);
    merge33(t0[1], t1[1], t2[1], t0[0], t1[0], t2[0]);

    float sx = src[(size_t)gid * 3 + 0];
    float sy = src[(size_t)gid * 3 + 1];
    float sz = src[(size_t)gid * 3 + 2];
    bool valid = (sx != 0.f) || (sy != 0.f) || (sz != 0.f);
    float qq = sx * sx + sy * sy + sz * sz;  // deferred |s|^2
    float s = valid ? (sqrtf(fmaxf(t0[0] + qq, 0.f)) + sqrtf(fmaxf(t1[0] + qq, 0.f)) +
                       sqrtf(fmaxf(t2[0] + qq, 0.f)))
                    : 0.f;
    float c = valid ? 1.f : 0.f;

    for (int off = 32; off >= 1; off >>= 1) {
        s += __shfl_down(s, off);
        c += __shfl_down(c, off);
    }
    __shared__ float red_s[4], red_c[4];
    int wave = threadIdx.x >> 6, lane = threadIdx.x & 63;
    if (lane == 0) { red_s[wave] = s; red_c[wave] = c; }
    __syncthreads();
    if (threadIdx.x == 0) {
        atomicAdd(&acc[b], red_s[0] + red_s[1] + red_s[2] + red_s[3]);
        atomicAdd(&cnt[b], red_c[0] + red_c[1] + red_c[2] + red_c[3]);
        __threadfence();
        unsigned t = atomicAdd(ticket, 1u);
        if (t == (unsigned)(MERGE_BLOCKS - 1)) {
            float loss = 0.f;
            #pragma unroll
            for (int bb = 0; bb < BATCH; ++bb) {
                float as = atomicAdd(&acc[bb], 0.f);
                float ac = atomicAdd(&cnt[bb], 0.f);
                loss += as / (ac * 3.0f);
            }
            out[0] = loss * (1.0f / BATCH);
        }
    }
}

extern "C" void kernel_launch(void* const* d_in, const int* in_sizes, int n_in,
                              void* d_out, int out_size, void* d_ws, size_t ws_size,
                              hipStream_t stream) {
    const float* src = (const float*)d_in[0];
    const float* tgt = (const float*)d_in[1];
    float* out = (float*)d_out;

    // ws: [0,16) acc[4]; [16,32) cnt[4]; [32,36) ticket; [256,...) partials
    // partials = 4 quarters x 3 x 32768 x 4B = 1.57 MB
    float* acc = (float*)d_ws;
    float* cnt = acc + 4;
    unsigned* ticket = (unsigned*)((char*)d_ws + 32);
    float* part = (float*)((char*)d_ws + 256);

    hipMemsetAsync(d_ws, 0, 64, stream);  // zero header (graph-capturable)

    dim3 g1(NQ, NG, BATCH);  // 4 x 32 x 4 = 512 blocks x 512 threads
    knn_partial<<<g1, 512, 0, stream>>>(src, tgt, part);
    knn_merge<<<dim3(MERGE_BLOCKS), 256, 0, stream>>>(src, part, acc, cnt,
                                                      ticket, out);
}